// Round 8
// baseline (348.428 us; speedup 1.0000x reference)
//
#include <hip/hip_runtime.h>
#include <hip/hip_bf16.h>
#include <math.h>

#define GRIDN 14
#define L 197
#define H 12
#define DK 64
#define D 768
#define B 32
#define BL (B*L)          // 6304
#define TOPK 32
#define NBH (B*H)         // 384
#define NROW (NBH*L)      // 75648
#define QKV_ELEMS ((size_t)NROW*DK)
#define KSTR 68           // K row stride in floats (float4-aligned)

typedef __attribute__((ext_vector_type(8))) short short8;   // 8 bf16
typedef __attribute__((ext_vector_type(4))) float floatx4;

__device__ __forceinline__ void load_lds16(void* lds, const void* g) {
    __builtin_amdgcn_global_load_lds(
        (const __attribute__((address_space(1))) unsigned int*)g,
        (__attribute__((address_space(3))) unsigned int*)lds, 16, 0, 0);
}

// ---------------------------------------------------------------------------
// prep: z<4 -> LDS-tiled transpose+cast of Wq/Wk/Wv/Wo to bf16 [n][k]
//        (Wq,Wk also emit lo-part); z==4 -> cast x to (hi,lo) bf16.
// ---------------------------------------------------------------------------
__global__ __launch_bounds__(256)
void prep(const float* __restrict__ x,
          const float* __restrict__ Wq, const float* __restrict__ Wk,
          const float* __restrict__ Wv, const float* __restrict__ Wo,
          __hip_bfloat16* __restrict__ xh, __hip_bfloat16* __restrict__ xl,
          __hip_bfloat16* __restrict__ WqTh, __hip_bfloat16* __restrict__ WqTl,
          __hip_bfloat16* __restrict__ WkTh, __hip_bfloat16* __restrict__ WkTl,
          __hip_bfloat16* __restrict__ WvT,  __hip_bfloat16* __restrict__ WoT)
{
    const int z = blockIdx.z;
    if (z == 4) {
        int lin = (blockIdx.y * 24 + blockIdx.x) * 256 + threadIdx.x;
        for (int i = lin; i < BL * D / 4; i += 24 * 24 * 256) {
            float4 v = ((const float4*)x)[i];
            union { __hip_bfloat16 b[4]; short4 s; } hh, ll;
            float f[4] = {v.x, v.y, v.z, v.w};
            #pragma unroll
            for (int j = 0; j < 4; ++j) {
                __hip_bfloat16 h = __float2bfloat16(f[j]);
                hh.b[j] = h;
                ll.b[j] = __float2bfloat16(f[j] - __bfloat162float(h));
            }
            ((short4*)xh)[i] = hh.s;
            ((short4*)xl)[i] = ll.s;
        }
        return;
    }
    __shared__ float tile[32][33];
    const float* src = (z == 0) ? Wq : (z == 1) ? Wk : (z == 2) ? Wv : Wo;
    __hip_bfloat16* dh = (z == 0) ? WqTh : (z == 1) ? WkTh : (z == 2) ? WvT : WoT;
    __hip_bfloat16* dl = (z == 0) ? WqTl : (z == 1) ? WkTl : nullptr;
    const int k0 = blockIdx.y * 32, n0 = blockIdx.x * 32;
    const int tx = threadIdx.x & 31, ty = threadIdx.x >> 5;

    for (int r = ty; r < 32; r += 8)
        tile[r][tx] = src[(size_t)(k0 + r) * D + n0 + tx];
    __syncthreads();
    for (int r = ty; r < 32; r += 8) {
        float v = tile[tx][r];
        __hip_bfloat16 h = __float2bfloat16(v);
        dh[(size_t)(n0 + r) * D + k0 + tx] = h;
        if (dl) dl[(size_t)(n0 + r) * D + k0 + tx] =
            __float2bfloat16(v - __bfloat162float(h));
    }
}

// ---------------------------------------------------------------------------
// Fused QKV GEMM: grid (50, 18). blockIdx.y/6 selects Q(3-term) / K(3-term)
// / V(1-term). 128x128 tile, TBK=32, XOR-swizzled LDS.
// ---------------------------------------------------------------------------
__global__ __launch_bounds__(256)
void gemm_qkv(const __hip_bfloat16* __restrict__ xh, const __hip_bfloat16* __restrict__ xl,
              const __hip_bfloat16* __restrict__ Wqh, const __hip_bfloat16* __restrict__ Wql,
              const __hip_bfloat16* __restrict__ Wkh, const __hip_bfloat16* __restrict__ Wkl,
              const __hip_bfloat16* __restrict__ Wvh,
              const float* __restrict__ bq, const float* __restrict__ bk,
              const float* __restrict__ bv,
              float* __restrict__ Qb, float* __restrict__ Kb, float* __restrict__ Vb)
{
    __shared__ __attribute__((aligned(16))) __hip_bfloat16 Ash[128 * 32];
    __shared__ __attribute__((aligned(16))) __hip_bfloat16 Bsh[128 * 32];
    __shared__ __attribute__((aligned(16))) __hip_bfloat16 Asl[128 * 32];
    __shared__ __attribute__((aligned(16))) __hip_bfloat16 Bsl[128 * 32];

    const int grp = blockIdx.y / 6, nt = blockIdx.y % 6;
    const __hip_bfloat16 *Bth, *Btl; const float* bias; float* C;
    if (grp == 0)      { Bth = Wqh; Btl = Wql; bias = bq; C = Qb; }
    else if (grp == 1) { Bth = Wkh; Btl = Wkl; bias = bk; C = Kb; }
    else               { Bth = Wvh; Btl = nullptr; bias = bv; C = Vb; }
    const bool split = (grp < 2);

    const int tid = threadIdx.x;
    const int wave = tid >> 6, lane = tid & 63;
    const int quad = lane >> 4, l16 = lane & 15;
    const int m0 = blockIdx.x * 128, n0 = nt * 128;
    const int wm = (wave & 1) * 64, wn = (wave >> 1) * 64;

    floatx4 acc[4][4] = {};

    int s_r[2], s_cs[2];
    #pragma unroll
    for (int u = 0; u < 2; ++u) {
        int idx = tid + u * 256;
        s_r[u] = idx >> 2; s_cs[u] = idx & 3;
    }

    for (int k0 = 0; k0 < D; k0 += 32) {
        #pragma unroll
        for (int u = 0; u < 2; ++u) {
            int r = s_r[u];
            int csrc = s_cs[u] ^ ((r >> 1) & 3);          // XOR swizzle
            int gm = m0 + r; if (gm >= BL) gm = BL - 1;
            size_t aoff = (size_t)gm * D + k0 + csrc * 8;
            size_t boff = (size_t)(n0 + r) * D + k0 + csrc * 8;
            int lds_off = (wave * 64 + u * 256) * 16;
            load_lds16((char*)Ash + lds_off, xh + aoff);
            load_lds16((char*)Bsh + lds_off, Bth + boff);
            if (split) {
                load_lds16((char*)Asl + lds_off, xl + aoff);
                load_lds16((char*)Bsl + lds_off, Btl + boff);
            }
        }
        __syncthreads();

        short8 ah[4], bh[4];
        #pragma unroll
        for (int a = 0; a < 4; ++a) {
            int r = wm + a * 16 + l16;
            int slot = (r << 2) + (quad ^ ((r >> 1) & 3));
            ah[a] = *(const short8*)((const char*)Ash + (slot << 4));
        }
        #pragma unroll
        for (int b2 = 0; b2 < 4; ++b2) {
            int r = wn + b2 * 16 + l16;
            int slot = (r << 2) + (quad ^ ((r >> 1) & 3));
            bh[b2] = *(const short8*)((const char*)Bsh + (slot << 4));
        }
        if (split) {
            short8 al[4], bl[4];
            #pragma unroll
            for (int a = 0; a < 4; ++a) {
                int r = wm + a * 16 + l16;
                int slot = (r << 2) + (quad ^ ((r >> 1) & 3));
                al[a] = *(const short8*)((const char*)Asl + (slot << 4));
            }
            #pragma unroll
            for (int b2 = 0; b2 < 4; ++b2) {
                int r = wn + b2 * 16 + l16;
                int slot = (r << 2) + (quad ^ ((r >> 1) & 3));
                bl[b2] = *(const short8*)((const char*)Bsl + (slot << 4));
            }
            #pragma unroll
            for (int a = 0; a < 4; ++a)
                #pragma unroll
                for (int b2 = 0; b2 < 4; ++b2) {
                    acc[a][b2] = __builtin_amdgcn_mfma_f32_16x16x32_bf16(
                        al[a], bh[b2], acc[a][b2], 0, 0, 0);
                    acc[a][b2] = __builtin_amdgcn_mfma_f32_16x16x32_bf16(
                        ah[a], bl[b2], acc[a][b2], 0, 0, 0);
                }
        }
        #pragma unroll
        for (int a = 0; a < 4; ++a)
            #pragma unroll
            for (int b2 = 0; b2 < 4; ++b2)
                acc[a][b2] = __builtin_amdgcn_mfma_f32_16x16x32_bf16(
                    ah[a], bh[b2], acc[a][b2], 0, 0, 0);
        __syncthreads();
    }

    #pragma unroll
    for (int b2 = 0; b2 < 4; ++b2) {
        int n = n0 + wn + b2 * 16 + l16;
        float bvv = bias[n];
        int hh = n >> 6, dd = n & 63;
        #pragma unroll
        for (int a = 0; a < 4; ++a) {
            #pragma unroll
            for (int r = 0; r < 4; ++r) {
                int m = m0 + wm + a * 16 + quad * 4 + r;
                if (m < BL) {
                    int bb = m / L, ll = m % L;
                    C[((((size_t)bb * H + hh) * L + ll) << 6) + dd] =
                        acc[a][b2][r] + bvv;
                }
            }
        }
    }
}

// ---------------------------------------------------------------------------
// O-projection GEMM: bf16 single-term, swizzled, row-major fp32 out.
// ---------------------------------------------------------------------------
__global__ __launch_bounds__(256)
void gemm_o(const __hip_bfloat16* __restrict__ A,
            const __hip_bfloat16* __restrict__ Bt,
            const float* __restrict__ bias, float* __restrict__ C)
{
    __shared__ __attribute__((aligned(16))) __hip_bfloat16 As[128 * 32];
    __shared__ __attribute__((aligned(16))) __hip_bfloat16 Bts[128 * 32];

    const int tid = threadIdx.x;
    const int wave = tid >> 6, lane = tid & 63;
    const int quad = lane >> 4, l16 = lane & 15;
    const int m0 = blockIdx.x * 128, n0 = blockIdx.y * 128;
    const int wm = (wave & 1) * 64, wn = (wave >> 1) * 64;

    floatx4 acc[4][4] = {};

    int s_r[2], s_cs[2];
    #pragma unroll
    for (int u = 0; u < 2; ++u) {
        int idx = tid + u * 256;
        s_r[u] = idx >> 2; s_cs[u] = idx & 3;
    }

    for (int k0 = 0; k0 < D; k0 += 32) {
        #pragma unroll
        for (int u = 0; u < 2; ++u) {
            int r = s_r[u];
            int csrc = s_cs[u] ^ ((r >> 1) & 3);
            int gm = m0 + r; if (gm >= BL) gm = BL - 1;
            int lds_off = (wave * 64 + u * 256) * 16;
            load_lds16((char*)As + lds_off, A + (size_t)gm * D + k0 + csrc * 8);
            load_lds16((char*)Bts + lds_off, Bt + (size_t)(n0 + r) * D + k0 + csrc * 8);
        }
        __syncthreads();

        short8 af[4], bf[4];
        #pragma unroll
        for (int a = 0; a < 4; ++a) {
            int r = wm + a * 16 + l16;
            int slot = (r << 2) + (quad ^ ((r >> 1) & 3));
            af[a] = *(const short8*)((const char*)As + (slot << 4));
        }
        #pragma unroll
        for (int b2 = 0; b2 < 4; ++b2) {
            int r = wn + b2 * 16 + l16;
            int slot = (r << 2) + (quad ^ ((r >> 1) & 3));
            bf[b2] = *(const short8*)((const char*)Bts + (slot << 4));
        }
        #pragma unroll
        for (int a = 0; a < 4; ++a)
            #pragma unroll
            for (int b2 = 0; b2 < 4; ++b2)
                acc[a][b2] = __builtin_amdgcn_mfma_f32_16x16x32_bf16(
                    af[a], bf[b2], acc[a][b2], 0, 0, 0);
        __syncthreads();
    }

    #pragma unroll
    for (int b2 = 0; b2 < 4; ++b2) {
        int n = n0 + wn + b2 * 16 + l16;
        float bvv = bias[n];
        #pragma unroll
        for (int a = 0; a < 4; ++a) {
            #pragma unroll
            for (int r = 0; r < 4; ++r) {
                int m = m0 + wm + a * 16 + quad * 4 + r;
                if (m < BL) C[(size_t)m * D + n] = acc[a][b2][r] + bvv;
            }
        }
    }
}

// ---------------------------------------------------------------------------
// Batched consensus GEMM: cons[b,i,h*64+d] = sum_j wout[b,h,i,j] * V[b,h,j,d]
// One block per (b,h). V transposed+bf16 in LDS (K padded to 224, zeros);
// wout staged per 32-wide K-chunk (fp32 coalesced loads -> bf16 LDS).
// Dense GEMM == reference einsum (zeros contribute nothing).
// ---------------------------------------------------------------------------
__global__ __launch_bounds__(256)
void gemm_cons(const float* __restrict__ Vg, const float* __restrict__ Wd,
               __hip_bfloat16* __restrict__ cons)
{
    __shared__ __attribute__((aligned(16))) __hip_bfloat16 Vt[64 * 224]; // [d][j]
    __shared__ __attribute__((aligned(16))) __hip_bfloat16 Aw[208 * 32]; // [i][k]

    const int bh = blockIdx.x;
    const int b = bh / H, h = bh % H;
    const int tid = threadIdx.x, wave = tid >> 6, lane = tid & 63;
    const int quad = lane >> 4, l16 = lane & 15;

    // zero-fill Vt (covers j-pad 197..223), then overwrite valid region
    for (int e = tid; e < 64 * 224 / 8; e += 256)
        *(short8*)&Vt[e * 8] = short8{0,0,0,0,0,0,0,0};
    __syncthreads();
    const float* Vp = Vg + (size_t)bh * L * DK;
    for (int idx = tid; idx < L * 16; idx += 256) {
        int j = idx >> 4, d4 = (idx & 15) * 4;
        float4 v = *(const float4*)&Vp[j * 64 + d4];
        Vt[(d4 + 0) * 224 + j] = __float2bfloat16(v.x);
        Vt[(d4 + 1) * 224 + j] = __float2bfloat16(v.y);
        Vt[(d4 + 2) * 224 + j] = __float2bfloat16(v.z);
        Vt[(d4 + 3) * 224 + j] = __float2bfloat16(v.w);
    }

    floatx4 acc[4][4] = {};   // [m-slot][n-tile]; m-tile = wave + 4*slot
    const size_t wbase = (size_t)bh * L * L;

    for (int kc = 0; kc < 7; ++kc) {
        __syncthreads();
        // stage A chunk: rows 0..207 x cols kc*32..+32 (reads beyond row 196 /
        // col 196 land in following valid memory; finite garbage x 0 = 0 or
        // discarded by the epilogue guard)
        for (int e = tid; e < 208 * 32; e += 256) {
            int r = e >> 5, k = e & 31;
            float w = Wd[wbase + (size_t)r * L + kc * 32 + k];
            Aw[e] = __float2bfloat16(w);
        }
        __syncthreads();

        short8 bf4[4];
        #pragma unroll
        for (int nt = 0; nt < 4; ++nt)
            bf4[nt] = *(const short8*)&Vt[(nt * 16 + l16) * 224 + kc * 32 + quad * 8];
        #pragma unroll
        for (int sl = 0; sl < 4; ++sl) {
            int mt = wave + sl * 4;
            if (mt < 13) {
                short8 af = *(const short8*)&Aw[(mt * 16 + l16) * 32 + quad * 8];
                #pragma unroll
                for (int nt = 0; nt < 4; ++nt)
                    acc[sl][nt] = __builtin_amdgcn_mfma_f32_16x16x32_bf16(
                        af, bf4[nt], acc[sl][nt], 0, 0, 0);
            }
        }
    }

    #pragma unroll
    for (int sl = 0; sl < 4; ++sl) {
        int mt = wave + sl * 4;
        if (mt >= 13) continue;
        #pragma unroll
        for (int nt = 0; nt < 4; ++nt) {
            #pragma unroll
            for (int r = 0; r < 4; ++r) {
                int i = mt * 16 + quad * 4 + r;
                if (i < L)
                    cons[((size_t)b * L + i) * D + h * 64 + nt * 16 + l16] =
                        __float2bfloat16(acc[sl][nt][r]);
            }
        }
    }
}

// ---------------------------------------------------------------------------
// Attention scores+softmax: grid (NBH, 2), 512 threads. K in LDS (stride 68),
// b128 score reads, Q register-prefetched, LUT-ified windows. Writes dense
// fp32 weights + mask only (consensus handled by gemm_cons).
// ---------------------------------------------------------------------------
__global__ __launch_bounds__(512)
void attn_fused(const float* __restrict__ Q, const float* __restrict__ Kg,
                const float* __restrict__ logsig,
                float* __restrict__ wout, float* __restrict__ mout)
{
    __shared__ __attribute__((aligned(16))) float KV[L * KSTR];
    __shared__ float qbuf[8][64];
    __shared__ float ws[8][32];
    __shared__ float clsbuf[L];
    __shared__ unsigned int winA[L];     // r0 | c0<<8 | Wd<<16 | Hh<<24
    __shared__ unsigned int winB[L];     // n | jbase<<8
    __shared__ unsigned char joff[76];   // [Wd-3][tm] -> (tm/Wd)*14 + tm%Wd

    const int bh = blockIdx.x;
    const int yb = blockIdx.y;
    const int tid = threadIdx.x, wave = tid >> 6, lane = tid & 63;
    const int half = lane & 1;

    // ---- LUTs ----
    if (tid >= 1 && tid < L) {
        int r = (tid - 1) / GRIDN, c = (tid - 1) % GRIDN;
        int r0 = r - 2 < 0 ? 0 : r - 2, r1 = r + 2 > 13 ? 13 : r + 2;
        int c0 = c - 2 < 0 ? 0 : c - 2, c1 = c + 2 > 13 ? 13 : c + 2;
        int Wd = c1 - c0 + 1, Hh = r1 - r0 + 1;
        winA[tid] = (unsigned)r0 | ((unsigned)c0 << 8) |
                    ((unsigned)Wd << 16) | ((unsigned)Hh << 24);
        winB[tid] = (unsigned)(Hh * Wd + 1) |
                    ((unsigned)(1 + r0 * GRIDN + c0) << 8);
    }
    if (tid == 0) { winA[0] = 0; winB[0] = 0; }
    if (tid < 75) {
        int w = tid / 25 + 3, tm = tid % 25;
        joff[tid] = (unsigned char)((tm / w) * GRIDN + tm % w);
    }

    int pr4[4], pc4[4];
    #pragma unroll
    for (int k = 0; k < 4; ++k) {
        int p = lane + (k << 6);
        if (p >= 1 && p < L) { pr4[k] = (p - 1) / GRIDN; pc4[k] = (p - 1) % GRIDN; }
        else                 { pr4[k] = 255; pc4[k] = 255; }
    }

    // ---- K staging ----
    const float* Kp = Kg + (size_t)bh * L * DK;
    for (int idx = tid; idx < L * 16; idx += 512) {
        int r = idx >> 4, c4 = idx & 15;
        *(float4*)&KV[r * KSTR + c4 * 4] = *(const float4*)&Kp[r * 64 + c4 * 4];
    }
    __syncthreads();

    const float coef = -0.5f * expf(-2.0f * logsig[0]);
    const int starts0[9] = {0, 9, 22, 35, 48, 61, 74, 87, 99};
    const int starts1[9] = {99, 112, 124, 136, 148, 161, 173, 185, 197};
    const int i_begin = yb ? starts1[wave] : starts0[wave];
    const int i_end   = yb ? starts1[wave + 1] : starts0[wave + 1];

    float qreg = (i_begin < i_end)
               ? Q[((size_t)bh * L + i_begin) * 64 + lane] : 0.f;

    for (int i = i_begin; i < i_end; ++i) {
        const int rowid = bh * L + i;
        const size_t wb = (size_t)rowid * L;

        qbuf[wave][lane] = qreg;
        if (i + 1 < i_end)
            qreg = Q[((size_t)rowid + 1) * 64 + lane];

        if (i == 0) {
            const float4* qp = (const float4*)&qbuf[wave][half << 5];
            for (int p = 0; p < 7; ++p) {
                int t = (p << 5) + (lane >> 1);
                bool valid = t < L;
                float s = 0.f;
                if (valid) {
                    const float4* kp = (const float4*)&KV[t * KSTR + (half << 5)];
                    #pragma unroll
                    for (int d4 = 0; d4 < 8; ++d4) {
                        float4 qv = qp[d4], kv = kp[d4];
                        float dx = qv.x - kv.x, dy = qv.y - kv.y;
                        float dz = qv.z - kv.z, dw = qv.w - kv.w;
                        s += dx * dx + dy * dy + dz * dz + dw * dw;
                    }
                }
                s += __shfl_xor(s, 1);
                if (valid && !half) clsbuf[t] = coef * s;
            }
            float orig[4], cur[4]; int selb = 0;
            #pragma unroll
            for (int k = 0; k < 4; ++k) {
                int t = lane + (k << 6);
                float v = (t < L) ? clsbuf[t] : -INFINITY;
                orig[k] = v; cur[k] = v;
            }
            float gmax = -INFINITY;
            for (int it = 0; it < TOPK; ++it) {
                float bv = cur[0]; int bt = lane;
                #pragma unroll
                for (int k = 1; k < 4; ++k)
                    if (cur[k] > bv) { bv = cur[k]; bt = lane + (k << 6); }
                #pragma unroll
                for (int off = 32; off; off >>= 1) {
                    float ov = __shfl_xor(bv, off);
                    int   ot = __shfl_xor(bt, off);
                    if (ov > bv || (ov == bv && ot < bt)) { bv = ov; bt = ot; }
                }
                if (it == 0) gmax = bv;
                if ((bt & 63) == lane) { cur[bt >> 6] = -INFINITY; selb |= 1 << (bt >> 6); }
            }
            float zl = 0.f; float wk[4];
            #pragma unroll
            for (int k = 0; k < 4; ++k) {
                wk[k] = ((selb >> k) & 1) ? expf(orig[k] - gmax) : 0.f;
                zl += wk[k];
            }
            #pragma unroll
            for (int off = 32; off; off >>= 1) zl += __shfl_xor(zl, off);

            #pragma unroll
            for (int k = 0; k < 4; ++k) {
                int p = lane + (k << 6);
                if (p < L) {
                    float wv = wk[k] / zl;
                    wout[wb + p] = wv;
                    mout[wb + p] = (wv > 1e-6f) ? 1.f : 0.f;
                }
            }
        } else {
            const unsigned wa = winA[i], wbp = winB[i];
            const int r0 = wa & 255, c0 = (wa >> 8) & 255;
            const int Wd2 = (wa >> 16) & 255, Hh = wa >> 24;
            const int n = wbp & 255, jbase = wbp >> 8;

            int t = lane >> 1;
            bool valid = t < n;
            float s = 0.f; int j = 0;
            if (valid) {
                if (t > 0) j = jbase + joff[(Wd2 - 3) * 25 + (t - 1)];
                const float4* kp = (const float4*)&KV[j * KSTR + (half << 5)];
                const float4* qp = (const float4*)&qbuf[wave][half << 5];
                #pragma unroll
                for (int d4 = 0; d4 < 8; ++d4) {
                    float4 qv = qp[d4], kv = kp[d4];
                    float dx = qv.x - kv.x, dy = qv.y - kv.y;
                    float dz = qv.z - kv.z, dw = qv.w - kv.w;
                    s += dx * dx + dy * dy + dz * dz + dw * dw;
                }
            }
            s += __shfl_xor(s, 1);
            float sc = valid ? coef * s : -INFINITY;

            float mx = sc;
            #pragma unroll
            for (int off = 32; off; off >>= 1) mx = fmaxf(mx, __shfl_xor(mx, off));
            float e = valid ? expf(sc - mx) : 0.f;
            float es = half ? 0.f : e;
            #pragma unroll
            for (int off = 32; off; off >>= 1) es += __shfl_xor(es, off);
            float wv = e / es;

            if (!half) ws[wave][t] = valid ? wv : 0.f;

            #pragma unroll
            for (int k = 0; k < 4; ++k) {
                int p = lane + (k << 6);
                if (p < L) {
                    float wd = 0.f;
                    if (p == 0) wd = ws[wave][0];
                    else {
                        unsigned du = (unsigned)(pr4[k] - r0);
                        unsigned dv = (unsigned)(pc4[k] - c0);
                        if (du < (unsigned)Hh && dv < (unsigned)Wd2)
                            wd = ws[wave][1 + du * Wd2 + dv];
                    }
                    wout[wb + p] = wd;
                    mout[wb + p] = (wd > 1e-6f) ? 1.f : 0.f;
                }
            }
        }
    }
}

// ---------------------------------------------------------------------------
extern "C" void kernel_launch(void* const* d_in, const int* in_sizes, int n_in,
                              void* d_out, int out_size, void* d_ws, size_t ws_size,
                              hipStream_t stream)
{
    const float* x   = (const float*)d_in[0];
    const float* Wq  = (const float*)d_in[1];
    const float* bq  = (const float*)d_in[2];
    const float* Wk  = (const float*)d_in[3];
    const float* bk  = (const float*)d_in[4];
    const float* Wv  = (const float*)d_in[5];
    const float* bv  = (const float*)d_in[6];
    const float* Wo  = (const float*)d_in[7];
    const float* bo  = (const float*)d_in[8];
    const float* lsg = (const float*)d_in[9];

    float* out  = (float*)d_out;                       // B*L*D
    float* wout = out + QKV_ELEMS;                     // B*H*L*L
    float* mout = wout + (size_t)B * H * L * L;        // B*H*L*L

    float* Qb  = (float*)d_ws;
    float* Kb  = Qb + QKV_ELEMS;
    float* Vb  = Kb + QKV_ELEMS;
    __hip_bfloat16* xh = (__hip_bfloat16*)(Vb + QKV_ELEMS);
    __hip_bfloat16* xl = xh + (size_t)BL * D;
    __hip_bfloat16* WqTh = xl + (size_t)BL * D;
    __hip_bfloat16* WqTl = WqTh + (size_t)D * D;
    __hip_bfloat16* WkTh = WqTl + (size_t)D * D;
    __hip_bfloat16* WkTl = WkTh + (size_t)D * D;
    __hip_bfloat16* WvT  = WkTl + (size_t)D * D;
    __hip_bfloat16* WoT  = WvT  + (size_t)D * D;
    __hip_bfloat16* consb = xh;   // alias: xh dead after gemm_qkv

    prep<<<dim3(24, 24, 5), 256, 0, stream>>>(
        x, Wq, Wk, Wv, Wo, xh, xl, WqTh, WqTl, WkTh, WkTl, WvT, WoT);

    gemm_qkv<<<dim3(50, 18), 256, 0, stream>>>(
        xh, xl, WqTh, WqTl, WkTh, WkTl, WvT, bq, bk, bv, Qb, Kb, Vb);

    attn_fused<<<dim3(NBH, 2), 512, 0, stream>>>(
        Qb, Kb, lsg, wout, mout);

    gemm_cons<<<NBH, 256, 0, stream>>>(Vb, wout, consb);

    gemm_o<<<dim3(50, 6), 256, 0, stream>>>(consb, WoT, bo, out);
}